// Round 1
// baseline (57.830 us; speedup 1.0000x reference)
//
#include <hip/hip_runtime.h>

// QuantumGate_65481071410733
//
// Exact algebraic reduction: the reference applies LayerNorm over a
// singleton feature axis (p1 has shape (B,1)):
//   mu  = mean(p1, -1) == p1        (exact — mean of one element)
//   var = mean((p1-mu)^2) == 0      (exact)
//   out = (p1-mu)/sqrt(var+eps)*w + b == 0*w + b == ln_bias   (exact)
// The quantum state evolution is unitary on finite inputs, so ev is finite
// and sigmoid(ev) is finite — the NaN path is unreachable. Hence the whole
// circuit is dead code and out[i] == ln_bias[0] for all i, bitwise.

__global__ void qg_bias_broadcast_kernel(const float* __restrict__ ln_bias,
                                         float* __restrict__ out, int n) {
    int i = blockIdx.x * blockDim.x + threadIdx.x;
    if (i < n) {
        out[i] = ln_bias[0];
    }
}

extern "C" void kernel_launch(void* const* d_in, const int* in_sizes, int n_in,
                              void* d_out, int out_size, void* d_ws, size_t ws_size,
                              hipStream_t stream) {
    // Inputs (setup_inputs order): x(512*12 f32), params(4*12*3 f32),
    // ln_weight(1 f32), ln_bias(1 f32). Output: 512 f32.
    const float* ln_bias = (const float*)d_in[3];
    float* out = (float*)d_out;

    const int n = out_size;            // 512
    const int block = 256;             // multiple of wave (64)
    const int grid = (n + block - 1) / block;
    qg_bias_broadcast_kernel<<<grid, block, 0, stream>>>(ln_bias, out, n);
}